// Round 21
// baseline (218.169 us; speedup 1.0000x reference)
//
#include <hip/hip_runtime.h>
#include <hip/hip_bf16.h>
#include <hip/hip_fp16.h>

#define HH 64
#define WW 64
#define HWSZ 4096
#define NBATCH 4
#define CCH 256
#define NPIX 16384   // NBATCH*HWSZ
#define CK 2304      // 9*256
#define EPSB 1e-5f

typedef __attribute__((ext_vector_type(8))) short bf16x8;
typedef __attribute__((ext_vector_type(4))) float f32x4;

static __device__ __forceinline__ unsigned short f2bf(float f){
  __hip_bfloat16 h = __float2bfloat16(f);
  return *(unsigned short*)&h;
}
static __device__ __forceinline__ float hfu(unsigned short u){
  __half h = *(__half*)&u;
  return __half2float(h);
}
static __device__ __forceinline__ unsigned short f2h(float f){
  __half h = __float2half(f);
  return *(unsigned short*)&h;
}

#if __has_builtin(__builtin_amdgcn_global_load_lds)
#define GLD(S,D) __builtin_amdgcn_global_load_lds((const __attribute__((address_space(1))) void*)(S), \
                                                  (__attribute__((address_space(3))) void*)(D), 16, 0, 0)
#else
#define GLD(S,D) (*(bf16x8*)((char*)(D) + (threadIdx.x & 63)*16) = *(const bf16x8*)(S))
#endif

// ---------------- transpose x (N,C,H,W) -> xTh (N,HW,C) fp16 ----------------
__global__ __launch_bounds__(256) void k_transpose_in(const float* __restrict__ x,
                                                      __half* __restrict__ xTh){
  __shared__ float tile[64][65];
  int hw0 = blockIdx.x * 64;
  int c0  = blockIdx.y * 64;
  int n   = blockIdx.z;
  int t = threadIdx.x;
  int col = t & 63, rb = t >> 6;
#pragma unroll
  for (int r = 0; r < 16; ++r){
    int cl = rb + r*4;
    tile[cl][col] = x[(size_t)(n*CCH + c0 + cl)*HWSZ + hw0 + col];
  }
  __syncthreads();
#pragma unroll
  for (int r = 0; r < 16; ++r){
    int hwl = rb + r*4;
    xTh[(size_t)(n*HWSZ + hw0 + hwl)*CCH + c0 + col] = __float2half(tile[col][hwl]);
  }
}

// ---------------- permute offset-conv weights to [k][j][c] (c contiguous) ----------------
__global__ void k_woff_perm(const float* __restrict__ tmw, const float* __restrict__ trw,
                            float* __restrict__ woff){
  int idx = blockIdx.x*256 + threadIdx.x;   // 9*6*256 = 13824
  if (idx >= 9*6*CCH) return;
  int k = idx / (6*CCH); int rem = idx % (6*CCH); int j = rem >> 8; int c = rem & 255;
  float v = (j < 4) ? tmw[(size_t)(j*CCH + c)*9 + k]
                    : trw[(size_t)((j-4)*CCH + c)*9 + k];
  woff[idx] = v;
}

// ---------------- pack dcn weights (Co,C,3,3) -> bf16 blocks [tap*8+cb][o][32ch],
// with LDS swizzle baked in: stored elem el holds logical c = el ^ (((o>>1)&3)<<3) ----------------
__global__ void k_wgemm_perm(const float* __restrict__ w, __hip_bfloat16* __restrict__ wp){
  int idx = blockIdx.x*256 + threadIdx.x;    // 589824 total
  if (idx >= CCH*CK) return;
  int blk = idx >> 13;        // tap*8 + cb  (72 blocks of 8192 elems)
  int e   = idx & 8191;
  int o   = e >> 5;
  int el  = e & 31;
  int tap = blk >> 3, cb = blk & 7;
  int c   = cb*32 + (el ^ (((o >> 1) & 3) << 3));
  wp[idx] = __float2bfloat16(w[(size_t)o*CK + c*9 + tap]);
}

// ---------------- offset generation: conv3x3(6ch) on fp16 src + make_offset ----------------
__global__ __launch_bounds__(256) void k_offsets(const __half* __restrict__ src,
    const float* __restrict__ wofft, const float* __restrict__ tmb,
    const float* __restrict__ trb, float* __restrict__ off){
  int t = threadIdx.x;
  int wid = t >> 6, lane = t & 63;
  int pbase = blockIdx.x*32 + wid*8;          // 512 blocks * 4 waves * 8 pixels
  int n = pbase >> 12; int hw = pbase & 4095; int h = hw >> 6; int w0 = hw & 63;
  const __half* base = src + (size_t)n*HWSZ*CCH + lane*4;

  float acc[8][6];
#pragma unroll
  for (int pi = 0; pi < 8; ++pi)
#pragma unroll
    for (int j = 0; j < 6; ++j) acc[pi][j] = 0.f;

  for (int k = 0; k < 9; ++k){
    int ky = k/3 - 1, kx = k%3 - 1;
    int yy = h + ky;
    if (yy < 0 || yy >= HH) continue;
    float4 wv[6];
#pragma unroll
    for (int j = 0; j < 6; ++j)
      wv[j] = *(const float4*)(wofft + ((k*6 + j) << 8) + lane*4);
#pragma unroll
    for (int pi = 0; pi < 8; ++pi){
      int xx = w0 + pi + kx;
      if (xx < 0 || xx >= WW) continue;
      ushort4 s4 = *(const ushort4*)(base + (size_t)(yy*WW + xx)*CCH);
      float f0 = hfu(s4.x), f1 = hfu(s4.y), f2 = hfu(s4.z), f3 = hfu(s4.w);
#pragma unroll
      for (int j = 0; j < 6; ++j)
        acc[pi][j] += f0*wv[j].x + f1*wv[j].y + f2*wv[j].z + f3*wv[j].w;
    }
  }

#pragma unroll
  for (int pi = 0; pi < 8; ++pi)
#pragma unroll
    for (int j = 0; j < 6; ++j){
      float v = acc[pi][j];
#pragma unroll
      for (int m = 32; m >= 1; m >>= 1) v += __shfl_xor(v, m);
      acc[pi][j] = v;
    }

  float b0 = tmb[0], b1 = tmb[1], b2 = tmb[2], b3 = tmb[3];
  float c0 = trb[0], c1 = trb[1];
  if (lane < 18){
    int k = lane >> 1, comp = lane & 1;
    float dy = (float)(k/3 - 1), dx = (float)(k%3 - 1);
#pragma unroll
    for (int pi = 0; pi < 8; ++pi){
      int p = pbase + pi;
      float val;
      if (comp == 0)
        val = (acc[pi][0] + b0)*dy + (acc[pi][1] + b1)*dx - dy + acc[pi][4] + c0;
      else
        val = (acc[pi][2] + b2)*dy + (acc[pi][3] + b3)*dx - dx + acc[pi][5] + c1;
      off[((size_t)p*9 + k)*2 + comp] = val;
    }
  }
}

// ---------------- fused deform-im2col + GEMM, FULL-DRAIN barriers, och-split ----------------
// Grid (512 pixel-tiles x 2 och-halves), 256 thr (4 waves). Tile 32px x 128och,
// 72 steps of 32ch (tap-major). Sync/gather path byte-identical to R20 (verified).
// B halves: 2 GLDs/step from wp's contiguous z*8KB sub-block (swizzle is z-invariant
// since (o>>1)&3 has period 8 and z offsets o by 128). LDS ~29KB -> 4-5 blocks/CU
// co-resident; cross-block overlap hides the per-step barrier drain latency.
struct Gset { ushort4 a, b, c, d; };

__global__ __launch_bounds__(256) void k_dcn(const __half* __restrict__ src,
    const float* __restrict__ off, const __hip_bfloat16* __restrict__ wp,
    float* __restrict__ gout, float* __restrict__ pbstats){
  __shared__ __hip_bfloat16 Al[2*32*32];     // 2 x 2KB
  __shared__ __hip_bfloat16 Bl[2*128*32];    // 2 x 8KB
  __shared__ __align__(16) int   t_off[288][4];
  __shared__ __align__(16) float t_w[288][4];

  int t = threadIdx.x;
  int bid = blockIdx.x;
  int z   = blockIdx.y;                      // och half: 0 or 1
  int tile = (bid & 7)*64 + (bid >> 3);      // XCD-bijective over 512
  int pbase = tile * 32;

  // ---- setup: 288 slots = 32 px x 9 taps ----
  for (int s = t; s < 288; s += 256){
    int px = s / 9, k = s - px*9;
    int p = pbase + px;
    int n = p >> 12; int hw = p & 4095; int h = hw >> 6; int w = hw & 63;
    float2 of = *(const float2*)(off + ((size_t)p*9 + k)*2);
    float py = (float)(h + k/3 - 1) + of.x;
    float px_ = (float)(w + (k - (k/3)*3) - 1) + of.y;
    float y0f = floorf(py), x0f = floorf(px_);
    float wy = py - y0f, wx = px_ - x0f;
    int y0 = (int)y0f, x0 = (int)x0f;
    int y1 = y0 + 1, x1 = x0 + 1;
    float w00 = (1.f-wy)*(1.f-wx), w01 = (1.f-wy)*wx;
    float w10 = wy*(1.f-wx),       w11 = wy*wx;
    if (y0 < 0 || y0 >= HH) { w00 = 0.f; w01 = 0.f; }
    if (y1 < 0 || y1 >= HH) { w10 = 0.f; w11 = 0.f; }
    if (x0 < 0 || x0 >= WW) { w00 = 0.f; w10 = 0.f; }
    if (x1 < 0 || x1 >= WW) { w01 = 0.f; w11 = 0.f; }
    int y0c = min(max(y0,0),HH-1), y1c = min(max(y1,0),HH-1);
    int x0c = min(max(x0,0),WW-1), x1c = min(max(x1,0),WW-1);
    int pbix = n << 12;
    t_off[s][0] = (pbix + y0c*WW + x0c) << 9;    // byte offset (256ch*2B per pixel)
    t_off[s][1] = (pbix + y0c*WW + x1c) << 9;
    t_off[s][2] = (pbix + y1c*WW + x0c) << 9;
    t_off[s][3] = (pbix + y1c*WW + x1c) << 9;
    t_w[s][0] = w00; t_w[s][1] = w01; t_w[s][2] = w10; t_w[s][3] = w11;
  }
  __syncthreads();

  int wid = t >> 6, lane = t & 63;
  int pxl = t >> 3, q = t & 7;               // gather role: px (0..31), channel-quad (4ch)
  const char* sbase = (const char*)src;
  const char* wpb = (const char*)wp + (size_t)z*8192;   // z's 128-och sub-block

  // A LDS write byte address (within one 2KB buffer): logical chunk q>>1, swizzled
  int abyte = pxl*64 + (((q >> 1) ^ ((pxl >> 1) & 3)) << 4) + (q & 1)*8;

  // frag read byte bases (within one buffer)
  int kq = lane >> 4, fr = lane & 15;
  int abr0, abr1, bbr0, bbr1;
  {
    int a0 = 0*16 + fr;  abr0 = a0*64 + ((kq ^ ((a0 >> 1) & 3)) << 4);
    int a1 = 1*16 + fr;  abr1 = a1*64 + ((kq ^ ((a1 >> 1) & 3)) << 4);
    int o0 = wid*32 + 0*16 + fr;  bbr0 = o0*64 + ((kq ^ ((o0 >> 1) & 3)) << 4);
    int o1 = wid*32 + 1*16 + fr;  bbr1 = o1*64 + ((kq ^ ((o1 >> 1) & 3)) << 4);
  }

  f32x4 acc[2][2];
#pragma unroll
  for (int i = 0; i < 2; ++i)
#pragma unroll
    for (int j = 0; j < 2; ++j)
      acc[i][j] = (f32x4){0.f,0.f,0.f,0.f};

  Gset gA, gB;

  auto issue_gather = [&](int ktn, Gset& g){
    int slot = pxl*9 + (ktn >> 3);
    int chb = ((ktn & 7) << 6) + (q << 3);   // 32ch half=64B, quad=8B (fp16)
    int4 o4 = *(const int4*)t_off[slot];
    g.a = *(const ushort4*)(sbase + (size_t)(unsigned)(o4.x + chb));
    g.b = *(const ushort4*)(sbase + (size_t)(unsigned)(o4.y + chb));
    g.c = *(const ushort4*)(sbase + (size_t)(unsigned)(o4.z + chb));
    g.d = *(const ushort4*)(sbase + (size_t)(unsigned)(o4.w + chb));
  };
  auto convert_write = [&](int ktc, Gset& g){
    int slot = pxl*9 + (ktc >> 3);
    float4 wv = *(const float4*)t_w[slot];
    float v0 = wv.x*hfu(g.a.x) + wv.y*hfu(g.b.x) + wv.z*hfu(g.c.x) + wv.w*hfu(g.d.x);
    float v1 = wv.x*hfu(g.a.y) + wv.y*hfu(g.b.y) + wv.z*hfu(g.c.y) + wv.w*hfu(g.d.y);
    float v2 = wv.x*hfu(g.a.z) + wv.y*hfu(g.b.z) + wv.z*hfu(g.c.z) + wv.w*hfu(g.d.z);
    float v3 = wv.x*hfu(g.a.w) + wv.y*hfu(g.b.w) + wv.z*hfu(g.c.w) + wv.w*hfu(g.d.w);
    ushort4 st; st.x = f2bf(v0); st.y = f2bf(v1); st.z = f2bf(v2); st.w = f2bf(v3);
    *(ushort4*)((char*)Al + (ktc & 1)*2048 + abyte) = st;
  };
  auto issue_B = [&](int ktb){
    const char* bsrc = wpb + (size_t)ktb*16384 + t*16;
    char* bdst = (char*)Bl + (ktb & 1)*8192 + wid*1024;
    GLD(bsrc,        bdst);
    GLD(bsrc + 4096, bdst + 4096);
  };

  // ---- prologue: B_0 staged; g_0,g_1 issued; A_0 written; full drain ----
  issue_B(0);
  asm volatile("" ::: "memory");
  issue_gather(0, gA);
  issue_gather(1, gB);
  convert_write(0, gA);
  __syncthreads();

  auto body = [&](int kt, Gset& gIss, Gset& gCnv){
    const char* Ac = (const char*)Al + (kt & 1)*2048;
    const char* Bc = (const char*)Bl + (kt & 1)*8192;
    bf16x8 av0 = *(const bf16x8*)(Ac + abr0);
    bf16x8 av1 = *(const bf16x8*)(Ac + abr1);
    bf16x8 bv0 = *(const bf16x8*)(Bc + bbr0);
    bf16x8 bv1 = *(const bf16x8*)(Bc + bbr1);
    if (kt <= 70) issue_B(kt + 1);
    asm volatile("" ::: "memory");            // pin: B GLDs issue before gathers
    if (kt <= 69) issue_gather(kt + 2, gIss);
    acc[0][0] = __builtin_amdgcn_mfma_f32_16x16x32_bf16(av0, bv0, acc[0][0], 0, 0, 0);
    acc[0][1] = __builtin_amdgcn_mfma_f32_16x16x32_bf16(av0, bv1, acc[0][1], 0, 0, 0);
    acc[1][0] = __builtin_amdgcn_mfma_f32_16x16x32_bf16(av1, bv0, acc[1][0], 0, 0, 0);
    acc[1][1] = __builtin_amdgcn_mfma_f32_16x16x32_bf16(av1, bv1, acc[1][1], 0, 0, 0);
    if (kt <= 70) convert_write(kt + 1, gCnv);
    __syncthreads();                          // full drain: vmcnt(0)+lgkmcnt(0)
  };

  for (int kk = 0; kk < 72; kk += 2){
    body(kk + 0, gA, gB);   // issue g_{kk+2} into gA, convert g_{kk+1} from gB
    body(kk + 1, gB, gA);   // issue g_{kk+3} into gB, convert g_{kk+2} from gA
  }

  // ---- epilogue: write gout + per-block partial stats (transposed plain stores) ----
#pragma unroll
  for (int mi = 0; mi < 2; ++mi)
#pragma unroll
    for (int ni = 0; ni < 2; ++ni){
      int rr = pbase + mi*16 + kq*4;
      int cc = (z << 7) + wid*32 + ni*16 + fr;
#pragma unroll
      for (int r = 0; r < 4; ++r)
        gout[(size_t)(rr + r)*CCH + cc] = acc[mi][ni][r];
    }
#pragma unroll
  for (int ni = 0; ni < 2; ++ni){
    float s = 0.f, ss = 0.f;
#pragma unroll
    for (int mi = 0; mi < 2; ++mi)
#pragma unroll
      for (int r = 0; r < 4; ++r){
        float v = acc[mi][ni][r];
        s += v; ss += v*v;
      }
    s  += __shfl_xor(s, 16);  s  += __shfl_xor(s, 32);
    ss += __shfl_xor(ss, 16); ss += __shfl_xor(ss, 32);
    if (kq == 0){
      int cc = (z << 7) + wid*32 + ni*16 + fr;
      pbstats[(size_t)cc*512 + bid]         = s;   // channel-contiguous partials
      pbstats[(size_t)(256 + cc)*512 + bid] = ss;
    }
  }
}

// ---------------- deterministic parallel stats reduce: 512 partials x 512 outputs ----------------
__global__ __launch_bounds__(256) void k_stats_reduce(const float* __restrict__ pb,
                                                      float* __restrict__ so){
  __shared__ float red[32][8];
  int t = threadIdx.x;
  int g = t >> 3, j = t & 7;
  int o = blockIdx.x*32 + g;          // 16*32 = 512 outputs (256 sums + 256 sumsq)
  const float4* p = (const float4*)(pb + (size_t)o*512 + j*64);
  float s = 0.f;
#pragma unroll
  for (int i = 0; i < 16; ++i){
    float4 v = p[i];
    s += v.x + v.y + v.z + v.w;
  }
  red[g][j] = s;
  __syncthreads();
  if (j == 0){
    float a = 0.f;
#pragma unroll
    for (int i = 0; i < 8; ++i) a += red[g][i];
    so[o] = a;
  }
}

// ---------------- BN apply + ReLU -> fp16 channels-last ----------------
__global__ __launch_bounds__(256) void k_bn_apply(const float* __restrict__ v,
    const float* __restrict__ stats, const float* __restrict__ g,
    const float* __restrict__ bb, __half* __restrict__ y){
  const float inv = 1.f/16384.f;
  const size_t total = (size_t)NPIX*CCH/4;
  for (size_t i4 = (size_t)blockIdx.x*256 + threadIdx.x; i4 < total;
       i4 += (size_t)gridDim.x*256){
    float4 vv = *(const float4*)&v[i4*4];
    int c = (int)((i4 & 63) << 2);
    float r[4] = {vv.x, vv.y, vv.z, vv.w};
    ushort4 st;
    unsigned short o[4];
#pragma unroll
    for (int j = 0; j < 4; ++j){
      float mean = stats[c+j]*inv;
      float var  = stats[CCH + c+j]*inv - mean*mean;
      float sc = g[c+j]*rsqrtf(var + EPSB);
      float sh = bb[c+j] - mean*sc;
      float val = fmaf(r[j], sc, sh);
      o[j] = f2h(val > 0.f ? val : 0.f);
    }
    st.x = o[0]; st.y = o[1]; st.z = o[2]; st.w = o[3];
    *(ushort4*)&y[i4*4] = st;
  }
}

// ---------------- final: BN2 + residual + ReLU, transpose to NCHW ----------------
__global__ __launch_bounds__(256) void k_final(const float* __restrict__ v,
    const float* __restrict__ stats, const float* __restrict__ g,
    const float* __restrict__ bb, const float* __restrict__ x,
    float* __restrict__ out){
  __shared__ float tile[64][65];
  int hw0 = blockIdx.x * 64;
  int o0  = blockIdx.y * 64;
  int n   = blockIdx.z;
  int t = threadIdx.x;
  int col = t & 63, rb = t >> 6;
  const float inv = 1.f/16384.f;
#pragma unroll
  for (int r = 0; r < 16; ++r){
    int pl = rb + r*4;
    tile[pl][col] = v[(size_t)(n*HWSZ + hw0 + pl)*CCH + o0 + col];
  }
  __syncthreads();
#pragma unroll
  for (int r = 0; r < 16; ++r){
    int ol = rb + r*4;
    int o = o0 + ol;
    float mean = stats[o]*inv;
    float var  = stats[CCH + o]*inv - mean*mean;
    float sc = g[o]*rsqrtf(var + EPSB);
    float sh = bb[o] - mean*sc;
    size_t gi = (size_t)(n*CCH + o)*HWSZ + hw0 + col;
    float val = fmaf(tile[col][ol], sc, sh) + x[gi];
    out[gi] = val > 0.f ? val : 0.f;
  }
}

extern "C" void kernel_launch(void* const* d_in, const int* in_sizes, int n_in,
                              void* d_out, int out_size, void* d_ws, size_t ws_size,
                              hipStream_t stream){
  const float* x     = (const float*)d_in[0];
  const float* tm1_w = (const float*)d_in[1];
  const float* tm1_b = (const float*)d_in[2];
  const float* tr1_w = (const float*)d_in[3];
  const float* tr1_b = (const float*)d_in[4];
  const float* dcn1_w= (const float*)d_in[5];
  const float* bn1_g = (const float*)d_in[6];
  const float* bn1_b = (const float*)d_in[7];
  const float* tm2_w = (const float*)d_in[8];
  const float* tm2_b = (const float*)d_in[9];
  const float* tr2_w = (const float*)d_in[10];
  const float* tr2_b = (const float*)d_in[11];
  const float* dcn2_w= (const float*)d_in[12];
  const float* bn2_g = (const float*)d_in[13];
  const float* bn2_b = (const float*)d_in[14];
  float* out = (float*)d_out;

  char* ws = (char*)d_ws;
  size_t cursor = 0;
  auto alloc = [&](size_t bytes)->char*{
    char* p = ws + cursor; cursor += (bytes + 255) & ~(size_t)255; return p;
  };
  __half* xTh = (__half*)alloc((size_t)NPIX*CCH*2);
  __half* ybh = (__half*)alloc((size_t)NPIX*CCH*2);
  float* gout  = (float*)alloc((size_t)NPIX*CCH*4);
  float* offb  = (float*)alloc((size_t)NPIX*9*2*4);
  float* woff1 = (float*)alloc(9*6*CCH*4);
  float* woff2 = (float*)alloc(9*6*CCH*4);
  __hip_bfloat16* wg1 = (__hip_bfloat16*)alloc((size_t)CCH*CK*2);
  __hip_bfloat16* wg2 = (__hip_bfloat16*)alloc((size_t)CCH*CK*2);
  float* stats = (float*)alloc(1024*4);
  float* pbstats = (float*)alloc((size_t)512*512*4);   // 1 MB per-block partials

  k_transpose_in<<<dim3(64,4,4),256,0,stream>>>(x, xTh);
  k_woff_perm<<<54,256,0,stream>>>(tm1_w, tr1_w, woff1);
  k_woff_perm<<<54,256,0,stream>>>(tm2_w, tr2_w, woff2);
  k_wgemm_perm<<<2304,256,0,stream>>>(dcn1_w, wg1);
  k_wgemm_perm<<<2304,256,0,stream>>>(dcn2_w, wg2);

  // ---- layer 1 ----
  k_offsets<<<512,256,0,stream>>>(xTh, woff1, tm1_b, tr1_b, offb);
  k_dcn<<<dim3(512,2),256,0,stream>>>(xTh, offb, wg1, gout, pbstats);
  k_stats_reduce<<<16,256,0,stream>>>(pbstats, stats);
  k_bn_apply<<<2048,256,0,stream>>>(gout, stats, bn1_g, bn1_b, ybh);

  // ---- layer 2 ----
  k_offsets<<<512,256,0,stream>>>(ybh, woff2, tm2_b, tr2_b, offb);
  k_dcn<<<dim3(512,2),256,0,stream>>>(ybh, offb, wg2, gout, pbstats);
  k_stats_reduce<<<16,256,0,stream>>>(pbstats, stats + 512);
  k_final<<<dim3(64,4,4),256,0,stream>>>(gout, stats + 512, bn2_g, bn2_b, x, out);
}

// Round 22
// 193.166 us; speedup vs baseline: 1.1294x; 1.1294x over previous
//
#include <hip/hip_runtime.h>
#include <hip/hip_bf16.h>

#define HH 64
#define WW 64
#define HWSZ 4096
#define NBATCH 4
#define CCH 256
#define NPIX 16384   // NBATCH*HWSZ
#define CK 2304      // 9*256
#define EPSB 1e-5f

typedef __attribute__((ext_vector_type(8))) short bf16x8;
typedef __attribute__((ext_vector_type(4))) float f32x4;

static __device__ __forceinline__ unsigned short f2bf(float f){
  __hip_bfloat16 h = __float2bfloat16(f);
  return *(unsigned short*)&h;
}

#if __has_builtin(__builtin_amdgcn_global_load_lds)
#define GLD(S,D) __builtin_amdgcn_global_load_lds((const __attribute__((address_space(1))) void*)(S), \
                                                  (__attribute__((address_space(3))) void*)(D), 16, 0, 0)
#else
#define GLD(S,D) (*(bf16x8*)((char*)(D) + (threadIdx.x & 63)*16) = *(const bf16x8*)(S))
#endif

// ---------------- transpose x (N,C,H,W) -> xT (N,HW,C) ----------------
__global__ __launch_bounds__(256) void k_transpose_in(const float* __restrict__ x,
                                                      float* __restrict__ xT){
  __shared__ float tile[64][65];
  int hw0 = blockIdx.x * 64;
  int c0  = blockIdx.y * 64;
  int n   = blockIdx.z;
  int t = threadIdx.x;
  int col = t & 63, rb = t >> 6;
#pragma unroll
  for (int r = 0; r < 16; ++r){
    int cl = rb + r*4;
    tile[cl][col] = x[(size_t)(n*CCH + c0 + cl)*HWSZ + hw0 + col];
  }
  __syncthreads();
#pragma unroll
  for (int r = 0; r < 16; ++r){
    int hwl = rb + r*4;
    xT[(size_t)(n*HWSZ + hw0 + hwl)*CCH + c0 + col] = tile[col][hwl];
  }
}

// ---------------- permute offset-conv weights to [k][j][c] (c contiguous) ----------------
__global__ void k_woff_perm(const float* __restrict__ tmw, const float* __restrict__ trw,
                            float* __restrict__ woff){
  int idx = blockIdx.x*256 + threadIdx.x;   // 9*6*256 = 13824
  if (idx >= 9*6*CCH) return;
  int k = idx / (6*CCH); int rem = idx % (6*CCH); int j = rem >> 8; int c = rem & 255;
  float v = (j < 4) ? tmw[(size_t)(j*CCH + c)*9 + k]
                    : trw[(size_t)((j-4)*CCH + c)*9 + k];
  woff[idx] = v;
}

// ---------------- pack dcn weights (Co,C,3,3) -> bf16 blocks [tap*8+cb][o][32ch],
// with LDS swizzle baked in: stored elem el holds logical c = el ^ (((o>>1)&3)<<3) ----------------
__global__ void k_wgemm_perm(const float* __restrict__ w, __hip_bfloat16* __restrict__ wp){
  int idx = blockIdx.x*256 + threadIdx.x;    // 589824 total
  if (idx >= CCH*CK) return;
  int blk = idx >> 13;        // tap*8 + cb  (72 blocks of 8192 elems)
  int e   = idx & 8191;
  int o   = e >> 5;
  int el  = e & 31;
  int tap = blk >> 3, cb = blk & 7;
  int c   = cb*32 + (el ^ (((o >> 1) & 3) << 3));
  wp[idx] = __float2bfloat16(w[(size_t)o*CK + c*9 + tap]);
}

// ---------------- offset generation: conv3x3(6ch) + make_offset, no LDS ----------------
__global__ __launch_bounds__(256) void k_offsets(const float* __restrict__ src,
    const float* __restrict__ wofft, const float* __restrict__ tmb,
    const float* __restrict__ trb, float* __restrict__ off){
  int t = threadIdx.x;
  int wid = t >> 6, lane = t & 63;
  int pbase = blockIdx.x*32 + wid*8;          // 512 blocks * 4 waves * 8 pixels
  int n = pbase >> 12; int hw = pbase & 4095; int h = hw >> 6; int w0 = hw & 63;
  const float* base = src + (size_t)n*HWSZ*CCH + lane*4;

  float acc[8][6];
#pragma unroll
  for (int pi = 0; pi < 8; ++pi)
#pragma unroll
    for (int j = 0; j < 6; ++j) acc[pi][j] = 0.f;

  for (int k = 0; k < 9; ++k){
    int ky = k/3 - 1, kx = k%3 - 1;
    int yy = h + ky;
    if (yy < 0 || yy >= HH) continue;
    float4 wv[6];
#pragma unroll
    for (int j = 0; j < 6; ++j)
      wv[j] = *(const float4*)(wofft + ((k*6 + j) << 8) + lane*4);
#pragma unroll
    for (int pi = 0; pi < 8; ++pi){
      int xx = w0 + pi + kx;
      if (xx < 0 || xx >= WW) continue;
      float4 s4 = *(const float4*)(base + (size_t)(yy*WW + xx)*CCH);
#pragma unroll
      for (int j = 0; j < 6; ++j)
        acc[pi][j] += s4.x*wv[j].x + s4.y*wv[j].y + s4.z*wv[j].z + s4.w*wv[j].w;
    }
  }

#pragma unroll
  for (int pi = 0; pi < 8; ++pi)
#pragma unroll
    for (int j = 0; j < 6; ++j){
      float v = acc[pi][j];
#pragma unroll
      for (int m = 32; m >= 1; m >>= 1) v += __shfl_xor(v, m);
      acc[pi][j] = v;
    }

  float b0 = tmb[0], b1 = tmb[1], b2 = tmb[2], b3 = tmb[3];
  float c0 = trb[0], c1 = trb[1];
  if (lane < 18){
    int k = lane >> 1, comp = lane & 1;
    float dy = (float)(k/3 - 1), dx = (float)(k%3 - 1);
#pragma unroll
    for (int pi = 0; pi < 8; ++pi){
      int p = pbase + pi;
      float val;
      if (comp == 0)
        val = (acc[pi][0] + b0)*dy + (acc[pi][1] + b1)*dx - dy + acc[pi][4] + c0;
      else
        val = (acc[pi][2] + b2)*dy + (acc[pi][3] + b3)*dx - dx + acc[pi][5] + c1;
      off[((size_t)p*9 + k)*2 + comp] = val;
    }
  }
}

// ---------------- fused deform-im2col + GEMM, FULL-DRAIN barriers (verified R17) ----------------
// Grid 512 (XCD-bijective), 256 thr (4 waves). Tile 32px x 256och, 72 steps of 32ch
// (tap-major). __syncthreads() per step (full vmcnt+lgkmcnt drain -- verified safe).
// A: gathers dist-2 in 2 reg sets, convert+ds_write 1 step ahead into 2x2KB swizzled
// LDS bufs. B: dist-1, 2 LDS bufs via global_load_lds from swizzled wp. LDS ~45KB.
// Epilogue: per-channel partials -> TRANSPOSED plain stores pbstats[cc*512+bid].
struct Gset { float4 a, b, c, d; };

__global__ __launch_bounds__(256) void k_dcn(const float* __restrict__ src,
    const float* __restrict__ off, const __hip_bfloat16* __restrict__ wp,
    float* __restrict__ gout, float* __restrict__ pbstats){
  __shared__ __hip_bfloat16 Al[2*32*32];     // 2 x 2KB
  __shared__ __hip_bfloat16 Bl[2*256*32];    // 2 x 16KB
  __shared__ __align__(16) int   t_off[288][4];
  __shared__ __align__(16) float t_w[288][4];

  int t = threadIdx.x;
  int bid = blockIdx.x;
  int tile = (bid & 7)*64 + (bid >> 3);      // XCD-bijective over 512
  int pbase = tile * 32;

  // ---- setup: 288 slots = 32 px x 9 taps ----
  for (int s = t; s < 288; s += 256){
    int px = s / 9, k = s - px*9;
    int p = pbase + px;
    int n = p >> 12; int hw = p & 4095; int h = hw >> 6; int w = hw & 63;
    float2 of = *(const float2*)(off + ((size_t)p*9 + k)*2);
    float py = (float)(h + k/3 - 1) + of.x;
    float px_ = (float)(w + (k - (k/3)*3) - 1) + of.y;
    float y0f = floorf(py), x0f = floorf(px_);
    float wy = py - y0f, wx = px_ - x0f;
    int y0 = (int)y0f, x0 = (int)x0f;
    int y1 = y0 + 1, x1 = x0 + 1;
    float w00 = (1.f-wy)*(1.f-wx), w01 = (1.f-wy)*wx;
    float w10 = wy*(1.f-wx),       w11 = wy*wx;
    if (y0 < 0 || y0 >= HH) { w00 = 0.f; w01 = 0.f; }
    if (y1 < 0 || y1 >= HH) { w10 = 0.f; w11 = 0.f; }
    if (x0 < 0 || x0 >= WW) { w00 = 0.f; w10 = 0.f; }
    if (x1 < 0 || x1 >= WW) { w01 = 0.f; w11 = 0.f; }
    int y0c = min(max(y0,0),HH-1), y1c = min(max(y1,0),HH-1);
    int x0c = min(max(x0,0),WW-1), x1c = min(max(x1,0),WW-1);
    int pbix = n << 12;
    t_off[s][0] = (pbix + y0c*WW + x0c) << 10;   // byte offset (256ch*4B per pixel)
    t_off[s][1] = (pbix + y0c*WW + x1c) << 10;
    t_off[s][2] = (pbix + y1c*WW + x0c) << 10;
    t_off[s][3] = (pbix + y1c*WW + x1c) << 10;
    t_w[s][0] = w00; t_w[s][1] = w01; t_w[s][2] = w10; t_w[s][3] = w11;
  }
  __syncthreads();

  int wid = t >> 6, lane = t & 63;
  int pxl = t >> 3, q = t & 7;               // gather role: px (0..31), channel-quad (4ch)
  const char* sbase = (const char*)src;
  const char* wpb = (const char*)wp;

  // A LDS write byte address (within one 2KB buffer): logical chunk q>>1, swizzled
  int abyte = pxl*64 + (((q >> 1) ^ ((pxl >> 1) & 3)) << 4) + (q & 1)*8;

  // frag read byte bases (within one buffer)
  int kq = lane >> 4, fr = lane & 15;
  int abr0, abr1, bbr0, bbr1, bbr2, bbr3;
  {
    int a0 = 0*16 + fr;  abr0 = a0*64 + ((kq ^ ((a0 >> 1) & 3)) << 4);
    int a1 = 1*16 + fr;  abr1 = a1*64 + ((kq ^ ((a1 >> 1) & 3)) << 4);
    int o0 = wid*64 + 0*16 + fr;  bbr0 = o0*64 + ((kq ^ ((o0 >> 1) & 3)) << 4);
    int o1 = wid*64 + 1*16 + fr;  bbr1 = o1*64 + ((kq ^ ((o1 >> 1) & 3)) << 4);
    int o2 = wid*64 + 2*16 + fr;  bbr2 = o2*64 + ((kq ^ ((o2 >> 1) & 3)) << 4);
    int o3 = wid*64 + 3*16 + fr;  bbr3 = o3*64 + ((kq ^ ((o3 >> 1) & 3)) << 4);
  }

  f32x4 acc[2][4];
#pragma unroll
  for (int i = 0; i < 2; ++i)
#pragma unroll
    for (int j = 0; j < 4; ++j)
      acc[i][j] = (f32x4){0.f,0.f,0.f,0.f};

  Gset gA, gB;

  auto issue_gather = [&](int ktn, Gset& g){
    int slot = pxl*9 + (ktn >> 3);
    int chb = ((ktn & 7) << 7) + (q << 4);
    int4 o4 = *(const int4*)t_off[slot];
    g.a = *(const float4*)(sbase + (size_t)(unsigned)(o4.x + chb));
    g.b = *(const float4*)(sbase + (size_t)(unsigned)(o4.y + chb));
    g.c = *(const float4*)(sbase + (size_t)(unsigned)(o4.z + chb));
    g.d = *(const float4*)(sbase + (size_t)(unsigned)(o4.w + chb));
  };
  auto convert_write = [&](int ktc, Gset& g){
    int slot = pxl*9 + (ktc >> 3);
    float4 wv = *(const float4*)t_w[slot];
    float v0 = wv.x*g.a.x + wv.y*g.b.x + wv.z*g.c.x + wv.w*g.d.x;
    float v1 = wv.x*g.a.y + wv.y*g.b.y + wv.z*g.c.y + wv.w*g.d.y;
    float v2 = wv.x*g.a.z + wv.y*g.b.z + wv.z*g.c.z + wv.w*g.d.z;
    float v3 = wv.x*g.a.w + wv.y*g.b.w + wv.z*g.c.w + wv.w*g.d.w;
    ushort4 st; st.x = f2bf(v0); st.y = f2bf(v1); st.z = f2bf(v2); st.w = f2bf(v3);
    *(ushort4*)((char*)Al + (ktc & 1)*2048 + abyte) = st;
  };
  auto issue_B = [&](int ktb){
    const char* bsrc = wpb + (size_t)ktb*16384 + t*16;
    char* bdst = (char*)Bl + (ktb & 1)*16384 + wid*1024;
    GLD(bsrc,                bdst);
    GLD(bsrc + 4096,         bdst + 4096);
    GLD(bsrc + 8192,         bdst + 8192);
    GLD(bsrc + 12288,        bdst + 12288);
  };

  // ---- prologue: B_0 staged; g_0,g_1 issued; A_0 written; full drain ----
  issue_B(0);
  asm volatile("" ::: "memory");
  issue_gather(0, gA);
  issue_gather(1, gB);
  convert_write(0, gA);
  __syncthreads();

  auto body = [&](int kt, Gset& gIss, Gset& gCnv){
    const char* Ac = (const char*)Al + (kt & 1)*2048;
    const char* Bc = (const char*)Bl + (kt & 1)*16384;
    bf16x8 av0 = *(const bf16x8*)(Ac + abr0);
    bf16x8 av1 = *(const bf16x8*)(Ac + abr1);
    bf16x8 bv0 = *(const bf16x8*)(Bc + bbr0);
    bf16x8 bv1 = *(const bf16x8*)(Bc + bbr1);
    bf16x8 bv2 = *(const bf16x8*)(Bc + bbr2);
    bf16x8 bv3 = *(const bf16x8*)(Bc + bbr3);
    if (kt <= 70) issue_B(kt + 1);
    asm volatile("" ::: "memory");            // pin: B GLDs issue before gathers
    if (kt <= 69) issue_gather(kt + 2, gIss);
    acc[0][0] = __builtin_amdgcn_mfma_f32_16x16x32_bf16(av0, bv0, acc[0][0], 0, 0, 0);
    acc[0][1] = __builtin_amdgcn_mfma_f32_16x16x32_bf16(av0, bv1, acc[0][1], 0, 0, 0);
    acc[0][2] = __builtin_amdgcn_mfma_f32_16x16x32_bf16(av0, bv2, acc[0][2], 0, 0, 0);
    acc[0][3] = __builtin_amdgcn_mfma_f32_16x16x32_bf16(av0, bv3, acc[0][3], 0, 0, 0);
    acc[1][0] = __builtin_amdgcn_mfma_f32_16x16x32_bf16(av1, bv0, acc[1][0], 0, 0, 0);
    acc[1][1] = __builtin_amdgcn_mfma_f32_16x16x32_bf16(av1, bv1, acc[1][1], 0, 0, 0);
    acc[1][2] = __builtin_amdgcn_mfma_f32_16x16x32_bf16(av1, bv2, acc[1][2], 0, 0, 0);
    acc[1][3] = __builtin_amdgcn_mfma_f32_16x16x32_bf16(av1, bv3, acc[1][3], 0, 0, 0);
    if (kt <= 70) convert_write(kt + 1, gCnv);
    __syncthreads();                          // full drain: vmcnt(0)+lgkmcnt(0)
  };

  for (int kk = 0; kk < 72; kk += 2){
    body(kk + 0, gA, gB);   // issue g_{kk+2} into gA, convert g_{kk+1} from gB
    body(kk + 1, gB, gA);   // issue g_{kk+3} into gB, convert g_{kk+2} from gA
  }

  // ---- epilogue: write gout + per-block partial stats (transposed plain stores) ----
#pragma unroll
  for (int mi = 0; mi < 2; ++mi)
#pragma unroll
    for (int ni = 0; ni < 4; ++ni){
      int rr = pbase + mi*16 + kq*4;
      int cc = wid*64 + ni*16 + fr;
#pragma unroll
      for (int r = 0; r < 4; ++r)
        gout[(size_t)(rr + r)*CCH + cc] = acc[mi][ni][r];
    }
#pragma unroll
  for (int ni = 0; ni < 4; ++ni){
    float s = 0.f, ss = 0.f;
#pragma unroll
    for (int mi = 0; mi < 2; ++mi)
#pragma unroll
      for (int r = 0; r < 4; ++r){
        float v = acc[mi][ni][r];
        s += v; ss += v*v;
      }
    s  += __shfl_xor(s, 16);  s  += __shfl_xor(s, 32);
    ss += __shfl_xor(ss, 16); ss += __shfl_xor(ss, 32);
    if (kq == 0){
      int cc = wid*64 + ni*16 + fr;
      pbstats[(size_t)cc*512 + bid]         = s;   // channel-contiguous partials
      pbstats[(size_t)(256 + cc)*512 + bid] = ss;
    }
  }
}

// ---------------- deterministic parallel stats reduce: 512 partials x 512 outputs ----------------
// 16 blocks x 256 thr; 8 threads per output, each sums 64 contiguous floats (float4),
// combined via LDS in fixed order -> bitwise deterministic across replays.
__global__ __launch_bounds__(256) void k_stats_reduce(const float* __restrict__ pb,
                                                      float* __restrict__ so){
  __shared__ float red[32][8];
  int t = threadIdx.x;
  int g = t >> 3, j = t & 7;
  int o = blockIdx.x*32 + g;          // 16*32 = 512 outputs (256 sums + 256 sumsq)
  const float4* p = (const float4*)(pb + (size_t)o*512 + j*64);
  float s = 0.f;
#pragma unroll
  for (int i = 0; i < 16; ++i){
    float4 v = p[i];
    s += v.x + v.y + v.z + v.w;
  }
  red[g][j] = s;
  __syncthreads();
  if (j == 0){
    float a = 0.f;
#pragma unroll
    for (int i = 0; i < 8; ++i) a += red[g][i];
    so[o] = a;
  }
}

// ---------------- BN apply + ReLU (channels-last in/out) ----------------
__global__ __launch_bounds__(256) void k_bn_apply(const float* __restrict__ v,
    const float* __restrict__ stats, const float* __restrict__ g,
    const float* __restrict__ bb, float* __restrict__ y){
  const float inv = 1.f/16384.f;
  for (size_t i = (size_t)blockIdx.x*256 + threadIdx.x; i < (size_t)NPIX*CCH;
       i += (size_t)gridDim.x*256){
    int c = (int)(i & 255);
    float mean = stats[c]*inv;
    float var  = stats[CCH + c]*inv - mean*mean;
    float sc = g[c]*rsqrtf(var + EPSB);
    float sh = bb[c] - mean*sc;
    float val = fmaf(v[i], sc, sh);
    y[i] = val > 0.f ? val : 0.f;
  }
}

// ---------------- final: BN2 + residual + ReLU, transpose to NCHW ----------------
__global__ __launch_bounds__(256) void k_final(const float* __restrict__ v,
    const float* __restrict__ stats, const float* __restrict__ g,
    const float* __restrict__ bb, const float* __restrict__ x,
    float* __restrict__ out){
  __shared__ float tile[64][65];
  int hw0 = blockIdx.x * 64;
  int o0  = blockIdx.y * 64;
  int n   = blockIdx.z;
  int t = threadIdx.x;
  int col = t & 63, rb = t >> 6;
  const float inv = 1.f/16384.f;
#pragma unroll
  for (int r = 0; r < 16; ++r){
    int pl = rb + r*4;
    tile[pl][col] = v[(size_t)(n*HWSZ + hw0 + pl)*CCH + o0 + col];
  }
  __syncthreads();
#pragma unroll
  for (int r = 0; r < 16; ++r){
    int ol = rb + r*4;
    int o = o0 + ol;
    float mean = stats[o]*inv;
    float var  = stats[CCH + o]*inv - mean*mean;
    float sc = g[o]*rsqrtf(var + EPSB);
    float sh = bb[o] - mean*sc;
    size_t gi = (size_t)(n*CCH + o)*HWSZ + hw0 + col;
    float val = fmaf(tile[col][ol], sc, sh) + x[gi];
    out[gi] = val > 0.f ? val : 0.f;
  }
}

extern "C" void kernel_launch(void* const* d_in, const int* in_sizes, int n_in,
                              void* d_out, int out_size, void* d_ws, size_t ws_size,
                              hipStream_t stream){
  const float* x     = (const float*)d_in[0];
  const float* tm1_w = (const float*)d_in[1];
  const float* tm1_b = (const float*)d_in[2];
  const float* tr1_w = (const float*)d_in[3];
  const float* tr1_b = (const float*)d_in[4];
  const float* dcn1_w= (const float*)d_in[5];
  const float* bn1_g = (const float*)d_in[6];
  const float* bn1_b = (const float*)d_in[7];
  const float* tm2_w = (const float*)d_in[8];
  const float* tm2_b = (const float*)d_in[9];
  const float* tr2_w = (const float*)d_in[10];
  const float* tr2_b = (const float*)d_in[11];
  const float* dcn2_w= (const float*)d_in[12];
  const float* bn2_g = (const float*)d_in[13];
  const float* bn2_b = (const float*)d_in[14];
  float* out = (float*)d_out;

  char* ws = (char*)d_ws;
  size_t cursor = 0;
  auto alloc = [&](size_t bytes)->char*{
    char* p = ws + cursor; cursor += (bytes + 255) & ~(size_t)255; return p;
  };
  float* xT    = (float*)alloc((size_t)NPIX*CCH*4);
  float* ybuf  = (float*)alloc((size_t)NPIX*CCH*4);
  float* gout  = (float*)alloc((size_t)NPIX*CCH*4);
  float* offb  = (float*)alloc((size_t)NPIX*9*2*4);
  float* woff1 = (float*)alloc(9*6*CCH*4);
  float* woff2 = (float*)alloc(9*6*CCH*4);
  __hip_bfloat16* wg1 = (__hip_bfloat16*)alloc((size_t)CCH*CK*2);
  __hip_bfloat16* wg2 = (__hip_bfloat16*)alloc((size_t)CCH*CK*2);
  float* stats = (float*)alloc(1024*4);
  float* pbstats = (float*)alloc((size_t)512*512*4);   // 1 MB per-block partials

  k_transpose_in<<<dim3(64,4,4),256,0,stream>>>(x, xT);
  k_woff_perm<<<54,256,0,stream>>>(tm1_w, tr1_w, woff1);
  k_woff_perm<<<54,256,0,stream>>>(tm2_w, tr2_w, woff2);
  k_wgemm_perm<<<2304,256,0,stream>>>(dcn1_w, wg1);
  k_wgemm_perm<<<2304,256,0,stream>>>(dcn2_w, wg2);

  // ---- layer 1 ----
  k_offsets<<<512,256,0,stream>>>(xT, woff1, tm1_b, tr1_b, offb);
  k_dcn<<<512,256,0,stream>>>(xT, offb, wg1, gout, pbstats);
  k_stats_reduce<<<16,256,0,stream>>>(pbstats, stats);
  k_bn_apply<<<2048,256,0,stream>>>(gout, stats, bn1_g, bn1_b, ybuf);

  // ---- layer 2 ----
  k_offsets<<<512,256,0,stream>>>(ybuf, woff2, tm2_b, tr2_b, offb);
  k_dcn<<<512,256,0,stream>>>(ybuf, offb, wg2, gout, pbstats);
  k_stats_reduce<<<16,256,0,stream>>>(pbstats, stats + 512);
  k_final<<<dim3(64,4,4),256,0,stream>>>(gout, stats + 512, bn2_g, bn2_b, x, out);
}